// Round 18
// baseline (64.872 us; speedup 1.0000x reference)
//
#include <hip/hip_runtime.h>
#include <hip/hip_bf16.h>

#define NH 16
#define QL 2048
#define KVL 4096
#define DH 64
#define PREFIX (KVL - QL)
#define NT 64                 // 64-kv tiles per head
#define TUS 8192              // ushorts per 64-tile: K frags 4096 | V frags 4096
#define PSTR32 34             // u32 per f16-partial row: 32 f16x2 + g
// scale * log2(e): softmax in base-2 domain (v_exp_f32 is exp2)
#define SCALE 0.18033688011112043f

typedef __attribute__((ext_vector_type(8))) _Float16 f16x8;
typedef __attribute__((ext_vector_type(2))) _Float16 f16x2;
typedef __attribute__((ext_vector_type(8))) short short8;
typedef __attribute__((ext_vector_type(4))) float f32x4;
typedef __attribute__((ext_vector_type(16))) float f32x16;
typedef unsigned int u32;

static __device__ __forceinline__ float exp2_fast(float x) {
    float r; asm("v_exp_f32 %0, %1" : "=v"(r) : "v"(x)); return r;
}
static __device__ __forceinline__ u32 pkrtz(float lo, float hi) {
    u32 r; asm("v_cvt_pkrtz_f16_f32 %0, %1, %2" : "=v"(r) : "v"(lo), "v"(hi)); return r;
}
static __device__ __forceinline__ void plswap(u32& x, u32& y) {
    asm("v_permlane32_swap_b32 %0, %1" : "+v"(x), "+v"(y));
}
#define MFMAH(a, b, c) __builtin_amdgcn_mfma_f32_32x32x16_f16(a, b, c, 0, 0, 0)

static __device__ __forceinline__ ushort f2bf(float x) {
    union { float f; u32 u; } v; v.f = x;
    u32 r = v.u + 0x7fffu + ((v.u >> 16) & 1u);
    return (ushort)(r >> 16);
}
static __device__ __forceinline__ float bf2f(ushort h) {
    union { u32 u; float f; } v; v.u = ((u32)h) << 16;
    return v.f;
}

// ---- precompute (merged): K and V^T -> per-(frag,lane) f16 layout in ws ----
__global__ void convKV(const float* __restrict__ K, const float* __restrict__ V,
                       ushort* __restrict__ ws) {
    const int half = blockIdx.x >> 11;                 // 0: K, 1: V
    const int gid  = (blockIdx.x & 2047) * 256 + threadIdx.x;  // 524288 each
    const int lane = gid & 63;
    const int fidx = (gid >> 6) & 7;
    const int tile = (gid >> 9) & 63;
    const int h    = gid >> 15;
    const int lq = lane & 31, hi = lane >> 5;
    f16x8 o;
    if (half == 0) {
        const int t = fidx >> 2, ks = fidx & 3;
        const int kv = tile * 64 + t * 32 + lq;
        const float* src = K + ((size_t)h * KVL + kv) * DH + ks * 16 + hi * 8;
        const float4 a = *(const float4*)src;
        const float4 b = *(const float4*)(src + 4);
        const float v[8] = {a.x, a.y, a.z, a.w, b.x, b.y, b.z, b.w};
        #pragma unroll
        for (int j = 0; j < 8; ++j) o[j] = (_Float16)v[j];
        *(f16x8*)(ws + (size_t)(h * NT + tile) * TUS + fidx * 512 + lane * 8) = o;
    } else {
        const int dt = fidx >> 2, ks = fidx & 3;
        const int d  = dt * 32 + lq;
        const float* src = V + ((size_t)h * KVL + tile * 64 + ks * 16 + hi * 8) * DH + d;
        #pragma unroll
        for (int j = 0; j < 8; ++j) o[j] = (_Float16)src[j * DH];
        *(f16x8*)(ws + (size_t)(h * NT + tile) * TUS + 4096 + fidx * 512 + lane * 8) = o;
    }
}

// ==== main: R17 grid/body + split QK chains (dep 4->2) + incremental ptrs ====
template<int NSPLIT>
__global__ __launch_bounds__(128, 4)
void sdpa_main(const float* __restrict__ Q, const ushort* __restrict__ ws,
               float* __restrict__ part)
{
    const int tid  = threadIdx.x;
    const int lane = tid & 63;
    const int w    = tid >> 6;         // 0..1
    const int lq   = lane & 31;
    const int hi   = lane >> 5;

    // LPT mapping: early bids = longest q-blocks (qw descending); 2 heads/XCD
    const int bid  = blockIdx.x;
    const int xcd  = bid & 7;
    const int rank = bid >> 3;
    int h, qw, sp;
    if constexpr (NSPLIT == 4) {       // 2048 blocks: rank = 0..255
        qw = 31 - (rank >> 3);
        const int rem = rank & 7;
        h  = xcd * 2 + (rem >> 2);
        sp = rem & 3;
    } else {                           // NSPLIT==2, 1024 blocks: rank = 0..127
        qw = 31 - (rank >> 2);
        const int rem = rank & 3;
        h  = xcd * 2 + (rem >> 1);
        sp = rem & 1;
    }
    const int qb  = qw * 64 + w * 32;
    const int ntt = (PREFIX + qw * 64 + 64) >> 5;
    const int t0  = (ntt * sp) / NSPLIT;
    const int t1  = (ntt * (sp + 1)) / NSPLIT;

    // ---- Q fragments, single-term f16, pre-scaled by scale*log2e ----
    f16x8 qh[4];
    {
        const float* qp = Q + ((size_t)h * QL + qb + lq) * DH + hi * 8;
        #pragma unroll
        for (int ks = 0; ks < 4; ++ks) {
            const float4 a = *(const float4*)(qp + ks * 16);
            const float4 b = *(const float4*)(qp + ks * 16 + 4);
            const float vv[8] = {a.x, a.y, a.z, a.w, b.x, b.y, b.z, b.w};
            #pragma unroll
            for (int jj = 0; jj < 8; ++jj)
                qh[ks][jj] = (_Float16)(vv[jj] * SCALE);
        }
    }

    f32x16 oacc[2];
    #pragma unroll
    for (int dt = 0; dt < 2; ++dt)
        #pragma unroll
        for (int r = 0; r < 16; ++r) oacc[dt][r] = 0.f;
    float m = 0.0f, lsum = 0.f;

    // ---- incremental per-lane pointers (no per-iter 64-bit muls) ----
    const ushort* hb = ws + (size_t)h * NT * TUS + lane * 8;
    const ushort* kp = hb + (size_t)(t0 >> 1) * TUS + (t0 & 1) * 2048;          // K(t0)
    const ushort* vp = hb + (size_t)(t0 >> 1) * TUS + 4096 + (t0 & 1) * 1024;   // V(t0)

    // ---- prologue: K(t0) into registers ----
    f16x8 kf[4];
    #pragma unroll
    for (int f = 0; f < 4; ++f) kf[f] = *(const f16x8*)(kp + f * 512);
    kp += (t0 & 1) ? 6144 : 2048;      // -> K(t0+1)

    for (int it = t0; it < t1; ++it) {
        // ---- V(it) loads; latency hides under QK + softmax ----
        f16x8 vf[4];
        vf[0] = *(const f16x8*)(vp);
        vf[1] = *(const f16x8*)(vp + 512);
        vf[2] = *(const f16x8*)(vp + 2048);
        vf[3] = *(const f16x8*)(vp + 2560);
        vp += (it & 1) ? 7168 : 1024;  // -> V(it+1)

        // ---- QK^T swapped, TWO independent 2-deep MFMA chains ----
        f32x16 sTa, sTb;
        #pragma unroll
        for (int r = 0; r < 16; ++r) { sTa[r] = 0.f; sTb[r] = 0.f; }
        __builtin_amdgcn_s_setprio(1);
        sTa = MFMAH(kf[0], qh[0], sTa);
        sTb = MFMAH(kf[2], qh[2], sTb);
        sTa = MFMAH(kf[1], qh[1], sTa);
        sTb = MFMAH(kf[3], qh[3], sTb);
        __builtin_amdgcn_s_setprio(0);

        // ---- prefetch K(it+1) into registers (kf dead after QK issue) ----
        f16x8 kfn[4];
        if (it + 1 < t1) {
            #pragma unroll
            for (int f = 0; f < 4; ++f) kfn[f] = *(const f16x8*)(kp + f * 512);
        }
        kp += (it & 1) ? 2048 : 6144;  // -> K(it+2)

        // ---- merge chains (off the MFMA pipe) ----
        f32x16 sT;
        #pragma unroll
        for (int r = 0; r < 16; ++r) sT[r] = sTa[r] + sTb[r];

        // ---- causal mask (boundary tiles; wave-uniform branch) ----
        const int kv0 = it * 32;
        if (kv0 + 32 > PREFIX + qb) {
            const int kvlim = PREFIX + qb + lq - kv0;
            #pragma unroll
            for (int r = 0; r < 16; ++r) {
                const int c = (r & 3) + 8 * (r >> 2) + 4 * hi;
                if (c > kvlim) sT[r] = -1e30f;
            }
        }

        // ---- online softmax, base-2, defer-max (THR=8), tree reductions ----
        float tmx[8];
        #pragma unroll
        for (int i = 0; i < 8; ++i) tmx[i] = fmaxf(sT[i], sT[i + 8]);
        #pragma unroll
        for (int ss = 4; ss > 0; ss >>= 1)
            #pragma unroll
            for (int i = 0; i < ss; ++i) tmx[i] = fmaxf(tmx[i], tmx[i + ss]);
        float mx = fmaxf(tmx[0], __shfl_xor(tmx[0], 32));
        if (__any(mx > m + 8.0f)) {
            const float mn  = fmaxf(m, mx);
            const float fsc = exp2_fast(m - mn);
            lsum *= fsc;
            #pragma unroll
            for (int dt = 0; dt < 2; ++dt)
                #pragma unroll
                for (int r = 0; r < 16; ++r) oacc[dt][r] *= fsc;
            m = mn;
        }
        #pragma unroll
        for (int r = 0; r < 16; ++r) sT[r] = exp2_fast(sT[r] - m);
        float ts[8];
        #pragma unroll
        for (int i = 0; i < 8; ++i) ts[i] = sT[i] + sT[i + 8];
        #pragma unroll
        for (int ss = 4; ss > 0; ss >>= 1)
            #pragma unroll
            for (int i = 0; i < ss; ++i) ts[i] += ts[i + ss];
        lsum += ts[0];

        // ---- P -> f16 frags in-register: cvt_pkrtz + permlane32_swap ----
        u32 x0 = pkrtz(sT[0],  sT[1]);
        u32 x1 = pkrtz(sT[2],  sT[3]);
        u32 y0 = pkrtz(sT[4],  sT[5]);
        u32 y1 = pkrtz(sT[6],  sT[7]);
        u32 x2 = pkrtz(sT[8],  sT[9]);
        u32 x3 = pkrtz(sT[10], sT[11]);
        u32 y2 = pkrtz(sT[12], sT[13]);
        u32 y3 = pkrtz(sT[14], sT[15]);
        plswap(x0, y0); plswap(x1, y1);
        plswap(x2, y2); plswap(x3, y3);
        union { u32 u[4]; f16x8 v; } p0, p1;
        p0.u[0] = x0; p0.u[1] = x1; p0.u[2] = y0; p0.u[3] = y1;
        p1.u[0] = x2; p1.u[1] = x3; p1.u[2] = y2; p1.u[3] = y3;

        // ---- PV: oacc[dt] += V^T-frag * P^T-frag ----
        __builtin_amdgcn_s_setprio(1);
        oacc[0] = MFMAH(vf[0], p0.v, oacc[0]);
        oacc[1] = MFMAH(vf[2], p0.v, oacc[1]);
        oacc[0] = MFMAH(vf[1], p1.v, oacc[0]);
        oacc[1] = MFMAH(vf[3], p1.v, oacc[1]);
        __builtin_amdgcn_s_setprio(0);

        // ---- rotate prefetched K ----
        if (it + 1 < t1) {
            #pragma unroll
            for (int f = 0; f < 4; ++f) kf[f] = kfn[f];
        }
    }

    // ---- epilogue: normalized f16 partial (32 u32 of f16 pairs + g) ----
    const float ltot = lsum + __shfl_xor(lsum, 32);
    const float linv = 1.0f / ltot;
    u32* pr = (u32*)part + ((size_t)(sp * NH + h) * QL + qb + lq) * PSTR32;
    #pragma unroll
    for (int dt = 0; dt < 2; ++dt)
        #pragma unroll
        for (int a = 0; a < 4; ++a) {
            const u32 w0 = pkrtz(oacc[dt][a * 4 + 0] * linv, oacc[dt][a * 4 + 1] * linv);
            const u32 w1 = pkrtz(oacc[dt][a * 4 + 2] * linv, oacc[dt][a * 4 + 3] * linv);
            pr[dt * 16 + a * 4 + hi * 2 + 0] = w0;
            pr[dt * 16 + a * 4 + hi * 2 + 1] = w1;
        }
    if (hi == 0) pr[32] = __float_as_uint(m + log2f(ltot));
}

// ---- combine N normalized-f16 partials: O = sum_j 2^(g_j-M) Ohat_j / sum_j 2^(g_j-M) ----
template<int N>
__global__ void combineH(const u32* __restrict__ part, float* __restrict__ O) {
    const int r = blockIdx.x * 8 + (threadIdx.x >> 5);   // h*QL + q
    const int p = threadIdx.x & 31;                      // u32 (column pair) index
    float g[N], M = -1e30f;
    #pragma unroll
    for (int j = 0; j < N; ++j) {
        g[j] = __uint_as_float(part[((size_t)j * NH * QL + r) * PSTR32 + 32]);
        M = fmaxf(M, g[j]);
    }
    float a0 = 0.f, a1 = 0.f, wsum = 0.f;
    #pragma unroll
    for (int j = 0; j < N; ++j) {
        const float wj = exp2f(g[j] - M);
        union { u32 u; f16x2 h; } v;
        v.u = part[((size_t)j * NH * QL + r) * PSTR32 + p];
        a0 += wj * (float)v.h[0];
        a1 += wj * (float)v.h[1];
        wsum += wj;
    }
    const float inv = 1.0f / wsum;
    float* op = O + (size_t)r * DH + p * 2;
    op[0] = a0 * inv;
    op[1] = a1 * inv;
}

// ================= fallback (round-1 kernel, proven, no ws needed) =================
#define QT 64
#define KBf 32
#define KSTR 72
#define VSTR 40
#define PSTR 40
#define SCALE_E 0.125f

__global__ __launch_bounds__(256, 2)
void sdpa_fallback(const float* __restrict__ Q, const float* __restrict__ K,
                   const float* __restrict__ V, float* __restrict__ O)
{
    __shared__ ushort sKh[KBf][KSTR];
    __shared__ ushort sKl[KBf][KSTR];
    __shared__ ushort sVt[DH][VSTR];
    __shared__ ushort sPf[4][16][PSTR];

    const int tid  = threadIdx.x;
    const int lane = tid & 63;
    const int w    = tid >> 6;
    const int h    = blockIdx.y;
    const int q0   = blockIdx.x * QT;
    const int qb   = q0 + w * 16;
    const int lrow = lane & 15;
    const int lgrp = lane >> 4;

    short8 qh[2], ql[2];
    {
        const float* qp = Q + ((size_t)h * QL + (qb + lrow)) * DH;
        #pragma unroll
        for (int dh = 0; dh < 2; ++dh) {
            const int d0 = dh * 32 + lgrp * 8;
            #pragma unroll
            for (int jj = 0; jj < 8; ++jj) {
                float x = qp[d0 + jj] * SCALE_E;
                ushort hb = f2bf(x);
                qh[dh][jj] = (short)hb;
                ql[dh][jj] = (short)f2bf(x - bf2f(hb));
            }
        }
    }

    f32x4 oacc[4];
    float m_r[4], l_r[4];
    #pragma unroll
    for (int n = 0; n < 4; ++n) { oacc[n][0]=0.f; oacc[n][1]=0.f; oacc[n][2]=0.f; oacc[n][3]=0.f; }
    #pragma unroll
    for (int r = 0; r < 4; ++r) { m_r[r] = -1e30f; l_r[r] = 0.f; }

    const int nkv = min(KVL, PREFIX + q0 + QT);

    for (int kv0 = 0; kv0 < nkv; kv0 += KBf) {
        __syncthreads();
        {
            const int r  = tid >> 3;
            const int d0 = (tid & 7) * 8;
            const float* kp = K + ((size_t)h * KVL + (kv0 + r)) * DH + d0;
            const float* vpp = V + ((size_t)h * KVL + (kv0 + r)) * DH + d0;
            short8 vh, vl;
            #pragma unroll
            for (int jj = 0; jj < 8; ++jj) {
                float x = kp[jj];
                ushort hb = f2bf(x);
                vh[jj] = (short)hb;
                vl[jj] = (short)f2bf(x - bf2f(hb));
            }
            *(short8*)&sKh[r][d0] = vh;
            *(short8*)&sKl[r][d0] = vl;
            #pragma unroll
            for (int jj = 0; jj < 8; ++jj)
                sVt[d0 + jj][r] = f2bf(vpp[jj]);
        }
        __syncthreads();

        f32x4 s[2];
        #pragma unroll
        for (int t = 0; t < 2; ++t) { s[t][0]=0.f; s[t][1]=0.f; s[t][2]=0.f; s[t][3]=0.f; }
        #pragma unroll
        for (int t = 0; t < 2; ++t) {
            #pragma unroll
            for (int dh = 0; dh < 2; ++dh) {
                const short8 kh = *(const short8*)&sKh[t*16 + lrow][dh*32 + lgrp*8];
                const short8 kl = *(const short8*)&sKl[t*16 + lrow][dh*32 + lgrp*8];
                s[t] = __builtin_amdgcn_mfma_f32_16x16x32_bf16(qh[dh], kh, s[t], 0, 0, 0);
                s[t] = __builtin_amdgcn_mfma_f32_16x16x32_bf16(qh[dh], kl, s[t], 0, 0, 0);
                s[t] = __builtin_amdgcn_mfma_f32_16x16x32_bf16(ql[dh], kh, s[t], 0, 0, 0);
            }
        }

        if (kv0 + KBf > PREFIX + qb) {
            #pragma unroll
            for (int t = 0; t < 2; ++t)
                #pragma unroll
                for (int r = 0; r < 4; ++r) {
                    const int kv = kv0 + t*16 + lrow;
                    const int q  = qb + lgrp*4 + r;
                    if (kv > PREFIX + q) s[t][r] = -1e30f;
                }
        }

        float tmax[4];
        #pragma unroll
        for (int r = 0; r < 4; ++r) tmax[r] = fmaxf(s[0][r], s[1][r]);
        #pragma unroll
        for (int offx = 1; offx <= 8; offx <<= 1)
            #pragma unroll
            for (int r = 0; r < 4; ++r) tmax[r] = fmaxf(tmax[r], __shfl_xor(tmax[r], offx, 64));

        float f[4];
        #pragma unroll
        for (int r = 0; r < 4; ++r) {
            const float mn = fmaxf(m_r[r], tmax[r]);
            f[r] = __expf(m_r[r] - mn);
            m_r[r] = mn;
        }
        #pragma unroll
        for (int t = 0; t < 2; ++t)
            #pragma unroll
            for (int r = 0; r < 4; ++r) s[t][r] = __expf(s[t][r] - m_r[r]);

        float rs[4];
        #pragma unroll
        for (int r = 0; r < 4; ++r) rs[r] = s[0][r] + s[1][r];
        #pragma unroll
        for (int offx = 1; offx <= 8; offx <<= 1)
            #pragma unroll
            for (int r = 0; r < 4; ++r) rs[r] += __shfl_xor(rs[r], offx, 64);
        #pragma unroll
        for (int r = 0; r < 4; ++r) l_r[r] = l_r[r] * f[r] + rs[r];
        #pragma unroll
        for (int n = 0; n < 4; ++n)
            #pragma unroll
            for (int r = 0; r < 4; ++r) oacc[n][r] *= f[r];

        #pragma unroll
        for (int t = 0; t < 2; ++t)
            #pragma unroll
            for (int r = 0; r < 4; ++r)
                sPf[w][lgrp*4 + r][t*16 + lrow] = f2bf(s[t][r]);
        asm volatile("s_waitcnt lgkmcnt(0)" ::: "memory");
        __builtin_amdgcn_sched_barrier(0);

        const short8 pa = *(const short8*)&sPf[w][lrow][lgrp*8];
        #pragma unroll
        for (int n = 0; n < 4; ++n) {
            const short8 vb = *(const short8*)&sVt[n*16 + lrow][lgrp*8];
            oacc[n] = __builtin_amdgcn_mfma_f32_16x16x32_bf16(pa, vb, oacc[n], 0, 0, 0);
        }
    }

    float inv[4];
    #pragma unroll
    for (int r = 0; r < 4; ++r) inv[r] = 1.0f / l_r[r];
    float* op = O + ((size_t)h * QL + qb) * DH;
    #pragma unroll
    for (int n = 0; n < 4; ++n)
        #pragma unroll
        for (int r = 0; r < 4; ++r)
            op[(lgrp*4 + r) * DH + n*16 + lrow] = oacc[n][r] * inv[r];
}

extern "C" void kernel_launch(void* const* d_in, const int* in_sizes, int n_in,
                              void* d_out, int out_size, void* d_ws, size_t ws_size,
                              hipStream_t stream) {
    const float* Q = (const float*)d_in[0];
    const float* K = (const float*)d_in[1];
    const float* V = (const float*)d_in[2];
    float* O = (float*)d_out;
    const size_t KVWS  = (size_t)NH * NT * TUS * 2;           // 16.78 MB
    const size_t PARTH = (size_t)NH * QL * PSTR32 * 4;        // 4.46 MB / f16 split
    ushort* wsKV = (ushort*)d_ws;
    float*  part = (float*)((char*)d_ws + KVWS);

    if (ws_size >= KVWS + 4 * PARTH) {
        hipLaunchKernelGGL(convKV, dim3(4096), dim3(256), 0, stream, K, V, wsKV);
        hipLaunchKernelGGL(sdpa_main<4>, dim3(2048), dim3(128), 0, stream, Q, wsKV, part);
        hipLaunchKernelGGL(combineH<4>, dim3(4096), dim3(256), 0, stream, (const u32*)part, O);
    } else if (ws_size >= KVWS + 2 * PARTH) {
        hipLaunchKernelGGL(convKV, dim3(4096), dim3(256), 0, stream, K, V, wsKV);
        hipLaunchKernelGGL(sdpa_main<2>, dim3(1024), dim3(128), 0, stream, Q, wsKV, part);
        hipLaunchKernelGGL(combineH<2>, dim3(4096), dim3(256), 0, stream, (const u32*)part, O);
    } else {
        hipLaunchKernelGGL(sdpa_fallback, dim3(32, 16), dim3(256), 0, stream, Q, K, V, O);
    }
}

// Round 19
// 61.821 us; speedup vs baseline: 1.0494x; 1.0494x over previous
//
#include <hip/hip_runtime.h>
#include <hip/hip_bf16.h>

#define NH 16
#define QL 2048
#define KVL 4096
#define DH 64
#define PREFIX (KVL - QL)
#define NT 64                 // 64-kv tiles per head
#define TUS 8192              // ushorts per 64-tile: K frags 4096 | V frags 4096
#define PSTR32 34             // u32 per f16-partial row: 32 f16x2 + g
// scale * log2(e): softmax in base-2 domain (v_exp_f32 is exp2)
#define SCALE 0.18033688011112043f

typedef __attribute__((ext_vector_type(8))) _Float16 f16x8;
typedef __attribute__((ext_vector_type(2))) _Float16 f16x2;
typedef __attribute__((ext_vector_type(8))) short short8;
typedef __attribute__((ext_vector_type(4))) float f32x4;
typedef __attribute__((ext_vector_type(16))) float f32x16;
typedef unsigned int u32;

static __device__ __forceinline__ float exp2_fast(float x) {
    float r; asm("v_exp_f32 %0, %1" : "=v"(r) : "v"(x)); return r;
}
static __device__ __forceinline__ u32 pkrtz(float lo, float hi) {
    u32 r; asm("v_cvt_pkrtz_f16_f32 %0, %1, %2" : "=v"(r) : "v"(lo), "v"(hi)); return r;
}
static __device__ __forceinline__ void plswap(u32& x, u32& y) {
    asm("v_permlane32_swap_b32 %0, %1" : "+v"(x), "+v"(y));
}
#define MFMAH(a, b, c) __builtin_amdgcn_mfma_f32_32x32x16_f16(a, b, c, 0, 0, 0)

static __device__ __forceinline__ ushort f2bf(float x) {
    union { float f; u32 u; } v; v.f = x;
    u32 r = v.u + 0x7fffu + ((v.u >> 16) & 1u);
    return (ushort)(r >> 16);
}
static __device__ __forceinline__ float bf2f(ushort h) {
    union { u32 u; float f; } v; v.u = ((u32)h) << 16;
    return v.f;
}

// ---- precompute (merged): K and V^T -> per-(frag,lane) f16 layout in ws ----
__global__ void convKV(const float* __restrict__ K, const float* __restrict__ V,
                       ushort* __restrict__ ws) {
    const int half = blockIdx.x >> 11;                 // 0: K, 1: V
    const int gid  = (blockIdx.x & 2047) * 256 + threadIdx.x;  // 524288 each
    const int lane = gid & 63;
    const int fidx = (gid >> 6) & 7;
    const int tile = (gid >> 9) & 63;
    const int h    = gid >> 15;
    const int lq = lane & 31, hi = lane >> 5;
    f16x8 o;
    if (half == 0) {
        const int t = fidx >> 2, ks = fidx & 3;
        const int kv = tile * 64 + t * 32 + lq;
        const float* src = K + ((size_t)h * KVL + kv) * DH + ks * 16 + hi * 8;
        const float4 a = *(const float4*)src;
        const float4 b = *(const float4*)(src + 4);
        const float v[8] = {a.x, a.y, a.z, a.w, b.x, b.y, b.z, b.w};
        #pragma unroll
        for (int j = 0; j < 8; ++j) o[j] = (_Float16)v[j];
        *(f16x8*)(ws + (size_t)(h * NT + tile) * TUS + fidx * 512 + lane * 8) = o;
    } else {
        const int dt = fidx >> 2, ks = fidx & 3;
        const int d  = dt * 32 + lq;
        const float* src = V + ((size_t)h * KVL + tile * 64 + ks * 16 + hi * 8) * DH + d;
        #pragma unroll
        for (int j = 0; j < 8; ++j) o[j] = (_Float16)src[j * DH];
        *(f16x8*)(ws + (size_t)(h * NT + tile) * TUS + 4096 + fidx * 512 + lane * 8) = o;
    }
}

// ==== main: R16 champion. 4 waves/block share ONE (head, 128-row q-block, sp) ====
// ==== -> L1 hits; K register-prefetch; no LDS, no barriers.                  ====
template<int NSPLIT>
__global__ __launch_bounds__(256, 4)
void sdpa_main(const float* __restrict__ Q, const ushort* __restrict__ ws,
               float* __restrict__ part)
{
    const int tid  = threadIdx.x;
    const int lane = tid & 63;
    const int w    = tid >> 6;
    const int lq   = lane & 31;
    const int hi   = lane >> 5;

    // mapping: 2 heads/XCD; block = (h, qB128, sp); wave w = rows qB*128+w*32..+31
    const int bid = blockIdx.x;
    const int xcd = bid & 7;
    const int k   = bid >> 3;
    int h, qb, sp, ntt;
    if constexpr (NSPLIT == 4) {       // 1024 blocks: k = 0..127
        const int hsub = k & 1;
        const int kk   = k >> 1;       // 0..63
        h   = xcd * 2 + hsub;
        const int qB = kk >> 2;        // 0..15 (128-row q-block)
        sp  = kk & 3;                  // shared by all 4 waves
        qb  = qB * 128 + w * 32;
        ntt = (PREFIX + qB * 128 + 128) >> 5;   // block-uniform tile count
    } else {                           // NSPLIT==2, 512 blocks: R9-style mapping
        h   = xcd * 2 + (k & 1);
        const int qwA = k >> 1;        // 0..31
        sp  = w >> 1;
        const int qw = (w & 1) ? (63 - qwA) : qwA;
        qb  = qw * 32;
        ntt = (PREFIX + qb + 32) >> 5;
    }
    const int t0 = (ntt * sp) / NSPLIT;
    const int t1 = (ntt * (sp + 1)) / NSPLIT;

    // ---- Q fragments, single-term f16, pre-scaled by scale*log2e ----
    f16x8 qh[4];
    {
        const float* qp = Q + ((size_t)h * QL + qb + lq) * DH + hi * 8;
        #pragma unroll
        for (int ks = 0; ks < 4; ++ks) {
            const float4 a = *(const float4*)(qp + ks * 16);
            const float4 b = *(const float4*)(qp + ks * 16 + 4);
            const float vv[8] = {a.x, a.y, a.z, a.w, b.x, b.y, b.z, b.w};
            #pragma unroll
            for (int jj = 0; jj < 8; ++jj)
                qh[ks][jj] = (_Float16)(vv[jj] * SCALE);
        }
    }

    f32x16 oacc[2];
    #pragma unroll
    for (int dt = 0; dt < 2; ++dt)
        #pragma unroll
        for (int r = 0; r < 16; ++r) oacc[dt][r] = 0.f;
    float m = 0.0f, lsum = 0.f;

    const ushort* hb = ws + (size_t)h * NT * TUS + lane * 8;

    // ---- prologue: K(t0) into registers ----
    f16x8 kf[4];
    {
        const ushort* bK = hb + (size_t)(t0 >> 1) * TUS + (t0 & 1) * 2048;
        #pragma unroll
        for (int f = 0; f < 4; ++f) kf[f] = *(const f16x8*)(bK + f * 512);
    }

    for (int it = t0; it < t1; ++it) {
        // ---- V(it) loads; latency hides under QK + softmax ----
        const ushort* b64 = hb + (size_t)(it >> 1) * TUS;
        const ushort* bV  = b64 + 4096 + (it & 1) * 1024;
        f16x8 vf[4];
        vf[0] = *(const f16x8*)(bV);
        vf[1] = *(const f16x8*)(bV + 512);
        vf[2] = *(const f16x8*)(bV + 2048);
        vf[3] = *(const f16x8*)(bV + 2560);

        // ---- QK^T swapped: sT[r] = S[kv=c(r,hi)][q=lq] (log2 domain) ----
        f32x16 sT;
        #pragma unroll
        for (int r = 0; r < 16; ++r) sT[r] = 0.f;
        __builtin_amdgcn_s_setprio(1);
        sT = MFMAH(kf[0], qh[0], sT);
        sT = MFMAH(kf[1], qh[1], sT);
        sT = MFMAH(kf[2], qh[2], sT);
        sT = MFMAH(kf[3], qh[3], sT);
        __builtin_amdgcn_s_setprio(0);

        // ---- prefetch K(it+1) into registers (kf dead after QK issue) ----
        f16x8 kfn[4];
        if (it + 1 < t1) {
            const ushort* bKn = hb + (size_t)((it + 1) >> 1) * TUS + ((it + 1) & 1) * 2048;
            #pragma unroll
            for (int f = 0; f < 4; ++f) kfn[f] = *(const f16x8*)(bKn + f * 512);
        }

        // ---- causal mask (boundary tiles; wave-uniform branch) ----
        const int kv0 = it * 32;
        if (kv0 + 32 > PREFIX + qb) {
            const int kvlim = PREFIX + qb + lq - kv0;
            #pragma unroll
            for (int r = 0; r < 16; ++r) {
                const int c = (r & 3) + 8 * (r >> 2) + 4 * hi;
                if (c > kvlim) sT[r] = -1e30f;
            }
        }

        // ---- online softmax, base-2, defer-max (THR=8), tree reductions ----
        float tmx[8];
        #pragma unroll
        for (int i = 0; i < 8; ++i) tmx[i] = fmaxf(sT[i], sT[i + 8]);
        #pragma unroll
        for (int ss = 4; ss > 0; ss >>= 1)
            #pragma unroll
            for (int i = 0; i < ss; ++i) tmx[i] = fmaxf(tmx[i], tmx[i + ss]);
        float mx = fmaxf(tmx[0], __shfl_xor(tmx[0], 32));
        if (__any(mx > m + 8.0f)) {
            const float mn  = fmaxf(m, mx);
            const float fsc = exp2_fast(m - mn);
            lsum *= fsc;
            #pragma unroll
            for (int dt = 0; dt < 2; ++dt)
                #pragma unroll
                for (int r = 0; r < 16; ++r) oacc[dt][r] *= fsc;
            m = mn;
        }
        #pragma unroll
        for (int r = 0; r < 16; ++r) sT[r] = exp2_fast(sT[r] - m);
        float ts[8];
        #pragma unroll
        for (int i = 0; i < 8; ++i) ts[i] = sT[i] + sT[i + 8];
        #pragma unroll
        for (int ss = 4; ss > 0; ss >>= 1)
            #pragma unroll
            for (int i = 0; i < ss; ++i) ts[i] += ts[i + ss];
        lsum += ts[0];

        // ---- P -> f16 frags in-register: cvt_pkrtz + permlane32_swap ----
        u32 x0 = pkrtz(sT[0],  sT[1]);
        u32 x1 = pkrtz(sT[2],  sT[3]);
        u32 y0 = pkrtz(sT[4],  sT[5]);
        u32 y1 = pkrtz(sT[6],  sT[7]);
        u32 x2 = pkrtz(sT[8],  sT[9]);
        u32 x3 = pkrtz(sT[10], sT[11]);
        u32 y2 = pkrtz(sT[12], sT[13]);
        u32 y3 = pkrtz(sT[14], sT[15]);
        plswap(x0, y0); plswap(x1, y1);
        plswap(x2, y2); plswap(x3, y3);
        union { u32 u[4]; f16x8 v; } p0, p1;
        p0.u[0] = x0; p0.u[1] = x1; p0.u[2] = y0; p0.u[3] = y1;
        p1.u[0] = x2; p1.u[1] = x3; p1.u[2] = y2; p1.u[3] = y3;

        // ---- PV: oacc[dt] += V^T-frag * P^T-frag ----
        __builtin_amdgcn_s_setprio(1);
        oacc[0] = MFMAH(vf[0], p0.v, oacc[0]);
        oacc[0] = MFMAH(vf[1], p1.v, oacc[0]);
        oacc[1] = MFMAH(vf[2], p0.v, oacc[1]);
        oacc[1] = MFMAH(vf[3], p1.v, oacc[1]);
        __builtin_amdgcn_s_setprio(0);

        // ---- rotate prefetched K ----
        if (it + 1 < t1) {
            #pragma unroll
            for (int f = 0; f < 4; ++f) kf[f] = kfn[f];
        }
    }

    // ---- epilogue: normalized f16 partial (32 u32 of f16 pairs + g) ----
    const float ltot = lsum + __shfl_xor(lsum, 32);
    const float linv = 1.0f / ltot;
    u32* pr = (u32*)part + ((size_t)(sp * NH + h) * QL + qb + lq) * PSTR32;
    #pragma unroll
    for (int dt = 0; dt < 2; ++dt)
        #pragma unroll
        for (int a = 0; a < 4; ++a) {
            const u32 w0 = pkrtz(oacc[dt][a * 4 + 0] * linv, oacc[dt][a * 4 + 1] * linv);
            const u32 w1 = pkrtz(oacc[dt][a * 4 + 2] * linv, oacc[dt][a * 4 + 3] * linv);
            pr[dt * 16 + a * 4 + hi * 2 + 0] = w0;
            pr[dt * 16 + a * 4 + hi * 2 + 1] = w1;
        }
    if (hi == 0) pr[32] = __float_as_uint(m + log2f(ltot));
}

// ---- combine N normalized-f16 partials: O = sum_j 2^(g_j-M) Ohat_j / sum_j 2^(g_j-M) ----
template<int N>
__global__ void combineH(const u32* __restrict__ part, float* __restrict__ O) {
    const int r = blockIdx.x * 8 + (threadIdx.x >> 5);   // h*QL + q
    const int p = threadIdx.x & 31;                      // u32 (column pair) index
    float g[N], M = -1e30f;
    #pragma unroll
    for (int j = 0; j < N; ++j) {
        g[j] = __uint_as_float(part[((size_t)j * NH * QL + r) * PSTR32 + 32]);
        M = fmaxf(M, g[j]);
    }
    float a0 = 0.f, a1 = 0.f, wsum = 0.f;
    #pragma unroll
    for (int j = 0; j < N; ++j) {
        const float wj = exp2f(g[j] - M);
        union { u32 u; f16x2 h; } v;
        v.u = part[((size_t)j * NH * QL + r) * PSTR32 + p];
        a0 += wj * (float)v.h[0];
        a1 += wj * (float)v.h[1];
        wsum += wj;
    }
    const float inv = 1.0f / wsum;
    float* op = O + (size_t)r * DH + p * 2;
    op[0] = a0 * inv;
    op[1] = a1 * inv;
}

// ================= fallback (round-1 kernel, proven, no ws needed) =================
#define QT 64
#define KBf 32
#define KSTR 72
#define VSTR 40
#define PSTR 40
#define SCALE_E 0.125f

__global__ __launch_bounds__(256, 2)
void sdpa_fallback(const float* __restrict__ Q, const float* __restrict__ K,
                   const float* __restrict__ V, float* __restrict__ O)
{
    __shared__ ushort sKh[KBf][KSTR];
    __shared__ ushort sKl[KBf][KSTR];
    __shared__ ushort sVt[DH][VSTR];
    __shared__ ushort sPf[4][16][PSTR];

    const int tid  = threadIdx.x;
    const int lane = tid & 63;
    const int w    = tid >> 6;
    const int h    = blockIdx.y;
    const int q0   = blockIdx.x * QT;
    const int qb   = q0 + w * 16;
    const int lrow = lane & 15;
    const int lgrp = lane >> 4;

    short8 qh[2], ql[2];
    {
        const float* qp = Q + ((size_t)h * QL + (qb + lrow)) * DH;
        #pragma unroll
        for (int dh = 0; dh < 2; ++dh) {
            const int d0 = dh * 32 + lgrp * 8;
            #pragma unroll
            for (int jj = 0; jj < 8; ++jj) {
                float x = qp[d0 + jj] * SCALE_E;
                ushort hb = f2bf(x);
                qh[dh][jj] = (short)hb;
                ql[dh][jj] = (short)f2bf(x - bf2f(hb));
            }
        }
    }

    f32x4 oacc[4];
    float m_r[4], l_r[4];
    #pragma unroll
    for (int n = 0; n < 4; ++n) { oacc[n][0]=0.f; oacc[n][1]=0.f; oacc[n][2]=0.f; oacc[n][3]=0.f; }
    #pragma unroll
    for (int r = 0; r < 4; ++r) { m_r[r] = -1e30f; l_r[r] = 0.f; }

    const int nkv = min(KVL, PREFIX + q0 + QT);

    for (int kv0 = 0; kv0 < nkv; kv0 += KBf) {
        __syncthreads();
        {
            const int r  = tid >> 3;
            const int d0 = (tid & 7) * 8;
            const float* kp = K + ((size_t)h * KVL + (kv0 + r)) * DH + d0;
            const float* vp = V + ((size_t)h * KVL + (kv0 + r)) * DH + d0;
            short8 vh, vl;
            #pragma unroll
            for (int jj = 0; jj < 8; ++jj) {
                float x = kp[jj];
                ushort hb = f2bf(x);
                vh[jj] = (short)hb;
                vl[jj] = (short)f2bf(x - bf2f(hb));
            }
            *(short8*)&sKh[r][d0] = vh;
            *(short8*)&sKl[r][d0] = vl;
            #pragma unroll
            for (int jj = 0; jj < 8; ++jj)
                sVt[d0 + jj][r] = f2bf(vp[jj]);
        }
        __syncthreads();

        f32x4 s[2];
        #pragma unroll
        for (int t = 0; t < 2; ++t) { s[t][0]=0.f; s[t][1]=0.f; s[t][2]=0.f; s[t][3]=0.f; }
        #pragma unroll
        for (int t = 0; t < 2; ++t) {
            #pragma unroll
            for (int dh = 0; dh < 2; ++dh) {
                const short8 kh = *(const short8*)&sKh[t*16 + lrow][dh*32 + lgrp*8];
                const short8 kl = *(const short8*)&sKl[t*16 + lrow][dh*32 + lgrp*8];
                s[t] = __builtin_amdgcn_mfma_f32_16x16x32_bf16(qh[dh], kh, s[t], 0, 0, 0);
                s[t] = __builtin_amdgcn_mfma_f32_16x16x32_bf16(qh[dh], kl, s[t], 0, 0, 0);
                s[t] = __builtin_amdgcn_mfma_f32_16x16x32_bf16(ql[dh], kh, s[t], 0, 0, 0);
            }
        }

        if (kv0 + KBf > PREFIX + qb) {
            #pragma unroll
            for (int t = 0; t < 2; ++t)
                #pragma unroll
                for (int r = 0; r < 4; ++r) {
                    const int kv = kv0 + t*16 + lrow;
                    const int q  = qb + lgrp*4 + r;
                    if (kv > PREFIX + q) s[t][r] = -1e30f;
                }
        }

        float tmax[4];
        #pragma unroll
        for (int r = 0; r < 4; ++r) tmax[r] = fmaxf(s[0][r], s[1][r]);
        #pragma unroll
        for (int offx = 1; offx <= 8; offx <<= 1)
            #pragma unroll
            for (int r = 0; r < 4; ++r) tmax[r] = fmaxf(tmax[r], __shfl_xor(tmax[r], offx, 64));

        float f[4];
        #pragma unroll
        for (int r = 0; r < 4; ++r) {
            const float mn = fmaxf(m_r[r], tmax[r]);
            f[r] = __expf(m_r[r] - mn);
            m_r[r] = mn;
        }
        #pragma unroll
        for (int t = 0; t < 2; ++t)
            #pragma unroll
            for (int r = 0; r < 4; ++r) s[t][r] = __expf(s[t][r] - m_r[r]);

        float rs[4];
        #pragma unroll
        for (int r = 0; r < 4; ++r) rs[r] = s[0][r] + s[1][r];
        #pragma unroll
        for (int offx = 1; offx <= 8; offx <<= 1)
            #pragma unroll
            for (int r = 0; r < 4; ++r) rs[r] += __shfl_xor(rs[r], offx, 64);
        #pragma unroll
        for (int r = 0; r < 4; ++r) l_r[r] = l_r[r] * f[r] + rs[r];
        #pragma unroll
        for (int n = 0; n < 4; ++n)
            #pragma unroll
            for (int r = 0; r < 4; ++r) oacc[n][r] *= f[r];

        #pragma unroll
        for (int t = 0; t < 2; ++t)
            #pragma unroll
            for (int r = 0; r < 4; ++r)
                sPf[w][lgrp*4 + r][t*16 + lrow] = f2bf(s[t][r]);
        asm volatile("s_waitcnt lgkmcnt(0)" ::: "memory");
        __builtin_amdgcn_sched_barrier(0);

        const short8 pa = *(const short8*)&sPf[w][lrow][lgrp*8];
        #pragma unroll
        for (int n = 0; n < 4; ++n) {
            const short8 vb = *(const short8*)&sVt[n*16 + lrow][lgrp*8];
            oacc[n] = __builtin_amdgcn_mfma_f32_16x16x32_bf16(pa, vb, oacc[n], 0, 0, 0);
        }
    }

    float inv[4];
    #pragma unroll
    for (int r = 0; r < 4; ++r) inv[r] = 1.0f / l_r[r];
    float* op = O + ((size_t)h * QL + qb) * DH;
    #pragma unroll
    for (int n = 0; n < 4; ++n)
        #pragma unroll
        for (int r = 0; r < 4; ++r)
            op[(lgrp*4 + r) * DH + n*16 + lrow] = oacc[n][r] * inv[r];
}

extern "C" void kernel_launch(void* const* d_in, const int* in_sizes, int n_in,
                              void* d_out, int out_size, void* d_ws, size_t ws_size,
                              hipStream_t stream) {
    const float* Q = (const float*)d_in[0];
    const float* K = (const float*)d_in[1];
    const float* V = (const float*)d_in[2];
    float* O = (float*)d_out;
    const size_t KVWS  = (size_t)NH * NT * TUS * 2;           // 16.78 MB
    const size_t PARTH = (size_t)NH * QL * PSTR32 * 4;        // 4.46 MB / f16 split
    ushort* wsKV = (ushort*)d_ws;
    float*  part = (float*)((char*)d_ws + KVWS);

    if (ws_size >= KVWS + 4 * PARTH) {
        hipLaunchKernelGGL(convKV, dim3(4096), dim3(256), 0, stream, K, V, wsKV);
        hipLaunchKernelGGL(sdpa_main<4>, dim3(1024), dim3(256), 0, stream, Q, wsKV, part);
        hipLaunchKernelGGL(combineH<4>, dim3(4096), dim3(256), 0, stream, (const u32*)part, O);
    } else if (ws_size >= KVWS + 2 * PARTH) {
        hipLaunchKernelGGL(convKV, dim3(4096), dim3(256), 0, stream, K, V, wsKV);
        hipLaunchKernelGGL(sdpa_main<2>, dim3(512), dim3(256), 0, stream, Q, wsKV, part);
        hipLaunchKernelGGL(combineH<2>, dim3(4096), dim3(256), 0, stream, (const u32*)part, O);
    } else {
        hipLaunchKernelGGL(sdpa_fallback, dim3(32, 16), dim3(256), 0, stream, Q, K, V, O);
    }
}